// Round 7
// baseline (918.180 us; speedup 1.0000x reference)
//
#include <hip/hip_runtime.h>

// RGCN 3-layer forward, MI355X — aggregate-first + bf16x3 split-precision MFMA,
// 2-phase A-pipeline, B weights direct global->VGPR (fragment-linear image).
//
// Per layer l:
//   aggF[d,r,:] = sum_{e: dst=d, et=r} h[src[e], :]                (gather, CSR by (dst,rel))
//   h' = [h | aggF0 | aggF1 | aggF2] @ [Wsl; W0; W1; W2] + bias    (K=512 MFMA GEMM)
// h stored as bf16 hi+lo pairs; GEMM uses 3 MFMAs per product
// (hi*hi + hi*lo + lo*hi; lo*lo ~2^-16 dropped) accumulating fp32.

#define DD 128

typedef __attribute__((ext_vector_type(8))) short short8;   // 8 bf16 = 4 VGPRs
typedef __attribute__((ext_vector_type(4))) float f32x4;

__device__ __forceinline__ float bf2f(ushort u) {
    return __uint_as_float(((unsigned)u) << 16);
}
__device__ __forceinline__ ushort f2bf(float f) {            // round-to-nearest-even
    unsigned b = __float_as_uint(f);
    return (ushort)((b + 0x7FFFu + ((b >> 16) & 1u)) >> 16);
}
__device__ __forceinline__ void splitbf(float f, ushort& hi, ushort& lo) {
    hi = f2bf(f);
    lo = f2bf(f - bf2f(hi));
}

#define GLOAD_LDS16(g, l)                                                      \
    __builtin_amdgcn_global_load_lds(                                          \
        (const __attribute__((address_space(1))) void*)(g),                    \
        (__attribute__((address_space(3))) void*)(l), 16, 0, 0)

// ===================== prep: split features into bf16 hi/lo =================
__global__ __launch_bounds__(256) void k_split_feat(
    const float* __restrict__ feat, ushort* __restrict__ h_hi,
    ushort* __restrict__ h_lo, int n4)
{
    int i = blockIdx.x * 256 + threadIdx.x;
    if (i >= n4) return;
    float4 v = reinterpret_cast<const float4*>(feat)[i];
    ushort4 hh, ll;
    splitbf(v.x, hh.x, ll.x); splitbf(v.y, hh.y, ll.y);
    splitbf(v.z, hh.z, ll.z); splitbf(v.w, hh.w, ll.w);
    reinterpret_cast<ushort4*>(h_hi)[i] = hh;
    reinterpret_cast<ushort4*>(h_lo)[i] = ll;
}

// ===================== prep: weights -> MFMA-fragment-linear image ==========
// bimg[l][chunk c][group g][lane v][j] = B[k = c*32 + (v>>4)*8 + j][col = g*16 + (v&15)]
// where B rows 0-127 = Wself[l], rows 128-511 = W[l] (r-major, i-major).
__global__ __launch_bounds__(256) void k_build_bimg(
    const float* __restrict__ W, const float* __restrict__ Wself,
    ushort* __restrict__ bh, ushort* __restrict__ bl_)
{
    int idx = blockIdx.x * 256 + threadIdx.x;
    if (idx >= 3 * 65536) return;
    int l = idx >> 16, rem = idx & 65535;
    int j = rem & 7, v = (rem >> 3) & 63, g = (rem >> 9) & 7, c = (rem >> 12) & 15;
    int col = g * 16 + (v & 15);
    int k = c * 32 + ((v >> 4) * 8) + j;
    float val;
    if (k < 128) val = Wself[((size_t)l * 128 + k) * 128 + col];
    else {
        int kk = k - 128, r = kk >> 7, i = kk & 127;
        val = W[(((size_t)l * 3 + r) * 128 + i) * 128 + col];
    }
    ushort hi, lo; splitbf(val, hi, lo);
    bh[idx] = hi; bl_[idx] = lo;
}

// ===================== CSR build over 3N bins (bin = dst*3 + et) ============
__global__ __launch_bounds__(256) void k_zero(int* __restrict__ p, int n) {
    int i = blockIdx.x * 256 + threadIdx.x;
    if (i < n) p[i] = 0;
}
__global__ __launch_bounds__(256) void k_hist3(
    const int* __restrict__ dst, const int* __restrict__ et,
    int* __restrict__ deg, int nEdges) {
    int e = blockIdx.x * 256 + threadIdx.x;
    if (e < nEdges) atomicAdd(&deg[dst[e] * 3 + et[e]], 1);
}
__global__ __launch_bounds__(1024) void k_scanA(
    const int* __restrict__ deg, int* __restrict__ off,
    int* __restrict__ chunkSum, int n) {
    __shared__ int s[1024];
    const int tid = threadIdx.x;
    const int i = blockIdx.x * 1024 + tid;
    int v = (i < n) ? deg[i] : 0;
    s[tid] = v;
    __syncthreads();
    for (int o = 1; o < 1024; o <<= 1) {
        int t = (tid >= o) ? s[tid - o] : 0;
        __syncthreads();
        s[tid] += t;
        __syncthreads();
    }
    if (i < n) off[i] = s[tid] - v;
    if (tid == 1023) chunkSum[blockIdx.x] = s[1023];
}
__global__ __launch_bounds__(512) void k_scanB(int* __restrict__ chunkSum, int nChunks) {
    __shared__ int s[512];
    const int tid = threadIdx.x;
    int v = (tid < nChunks) ? chunkSum[tid] : 0;
    s[tid] = v;
    __syncthreads();
    for (int o = 1; o < 512; o <<= 1) {
        int t = (tid >= o) ? s[tid - o] : 0;
        __syncthreads();
        s[tid] += t;
        __syncthreads();
    }
    if (tid < nChunks) chunkSum[tid] = s[tid] - v;
}
__global__ __launch_bounds__(256) void k_scanC(
    int* __restrict__ off, int* __restrict__ pos,
    const int* __restrict__ chunkBase, int n, int total) {
    int i = blockIdx.x * 256 + threadIdx.x;
    if (i < n) {
        int o = off[i] + chunkBase[i >> 10];
        off[i] = o;
        pos[i] = o;
    }
    if (i == 0) off[n] = total;
}
__global__ __launch_bounds__(256) void k_scatter3(
    const int* __restrict__ src, const int* __restrict__ dst,
    const int* __restrict__ et, int* __restrict__ pos,
    int* __restrict__ csr, int nEdges) {
    int e = blockIdx.x * 256 + threadIdx.x;
    if (e < nEdges) {
        int j = atomicAdd(&pos[dst[e] * 3 + et[e]], 1);
        csr[j] = src[e];
    }
}

// ===================== gather: aggF[n,r,:] = sum h[src] (bf16 hi/lo) ========
// One 32-lane half-wave per dst node; lane owns elements li*4..li*4+3.
// 4-deep unroll: up to 8 row-reads in flight per half-wave.
__global__ __launch_bounds__(256) void rgcn_gather(
    const ushort* __restrict__ h_hi, const ushort* __restrict__ h_lo,
    const int* __restrict__ off3, const int* __restrict__ csr,
    ushort* __restrict__ aggF_hi, ushort* __restrict__ aggF_lo,
    int nNodes)
{
    const int gtid = blockIdx.x * 256 + threadIdx.x;
    const int gw   = gtid >> 6;
    const int lane = threadIdx.x & 63;
    const int sub  = lane >> 5;
    const int li   = lane & 31;
    const int n    = gw * 2 + sub;
    if (n >= nNodes) return;
    const int e0 = li * 4;

    #pragma unroll
    for (int r = 0; r < 3; ++r) {
        const int b = off3[n * 3 + r];
        const int e = off3[n * 3 + r + 1];
        float ax = 0.f, ay = 0.f, az = 0.f, aw = 0.f;
        int j = b;
        for (; j + 3 < e; j += 4) {
            int s0 = csr[j], s1 = csr[j + 1], s2 = csr[j + 2], s3 = csr[j + 3];
            ushort4 h0 = *reinterpret_cast<const ushort4*>(h_hi + (size_t)s0 * DD + e0);
            ushort4 l0 = *reinterpret_cast<const ushort4*>(h_lo + (size_t)s0 * DD + e0);
            ushort4 h1 = *reinterpret_cast<const ushort4*>(h_hi + (size_t)s1 * DD + e0);
            ushort4 l1 = *reinterpret_cast<const ushort4*>(h_lo + (size_t)s1 * DD + e0);
            ushort4 h2 = *reinterpret_cast<const ushort4*>(h_hi + (size_t)s2 * DD + e0);
            ushort4 l2 = *reinterpret_cast<const ushort4*>(h_lo + (size_t)s2 * DD + e0);
            ushort4 h3 = *reinterpret_cast<const ushort4*>(h_hi + (size_t)s3 * DD + e0);
            ushort4 l3 = *reinterpret_cast<const ushort4*>(h_lo + (size_t)s3 * DD + e0);
            ax += (bf2f(h0.x) + bf2f(l0.x)) + (bf2f(h1.x) + bf2f(l1.x))
                + (bf2f(h2.x) + bf2f(l2.x)) + (bf2f(h3.x) + bf2f(l3.x));
            ay += (bf2f(h0.y) + bf2f(l0.y)) + (bf2f(h1.y) + bf2f(l1.y))
                + (bf2f(h2.y) + bf2f(l2.y)) + (bf2f(h3.y) + bf2f(l3.y));
            az += (bf2f(h0.z) + bf2f(l0.z)) + (bf2f(h1.z) + bf2f(l1.z))
                + (bf2f(h2.z) + bf2f(l2.z)) + (bf2f(h3.z) + bf2f(l3.z));
            aw += (bf2f(h0.w) + bf2f(l0.w)) + (bf2f(h1.w) + bf2f(l1.w))
                + (bf2f(h2.w) + bf2f(l2.w)) + (bf2f(h3.w) + bf2f(l3.w));
        }
        for (; j < e; ++j) {
            int s0 = csr[j];
            ushort4 h0 = *reinterpret_cast<const ushort4*>(h_hi + (size_t)s0 * DD + e0);
            ushort4 l0 = *reinterpret_cast<const ushort4*>(h_lo + (size_t)s0 * DD + e0);
            ax += bf2f(h0.x) + bf2f(l0.x);
            ay += bf2f(h0.y) + bf2f(l0.y);
            az += bf2f(h0.z) + bf2f(l0.z);
            aw += bf2f(h0.w) + bf2f(l0.w);
        }
        const size_t o = ((size_t)n * 3 + r) * DD + e0;
        ushort4 hh, ll;
        splitbf(ax, hh.x, ll.x); splitbf(ay, hh.y, ll.y);
        splitbf(az, hh.z, ll.z); splitbf(aw, hh.w, ll.w);
        *reinterpret_cast<ushort4*>(aggF_hi + o) = hh;
        *reinterpret_cast<ushort4*>(aggF_lo + o) = ll;
    }
}

// ===================== MFMA GEMM: [h|aggF] @ Bfused + bias ==================
// 128x128 tile per block, 4 waves (2x2), each wave 64x64 = 4x4 frags of 16x16.
// A: 2-phase double-buffered LDS via global_load_lds (fragment-linear).
// B: fragment-linear global image (L2-hot, 256 KB) loaded direct to VGPR.
// 3 MFMAs per product: ah*bh + ah*bl + al*bh (lo*lo dropped, ~2^-16).
__global__ __launch_bounds__(256) void rgcn_mfma(
    const ushort* __restrict__ h_hi, const ushort* __restrict__ h_lo,       // [N,128]
    const ushort* __restrict__ aggF_hi, const ushort* __restrict__ aggF_lo, // [N,384]
    const ushort* __restrict__ bimg_hi, const ushort* __restrict__ bimg_lo, // layer's 65536
    const float* __restrict__ bl,                                           // [128]
    ushort* __restrict__ out_hi, ushort* __restrict__ out_lo,               // layers 0,1
    float* __restrict__ out_f32,                                            // layer 2
    int isFinal, int nNodes)
{
    __shared__ ushort Ah[2][4096];          // 16 KB
    __shared__ ushort Al[2][4096];          // 16 KB (total 32 KB)

    const int t = threadIdx.x;
    const int w = t >> 6;                   // wave 0..3
    const int lane = t & 63;
    const int wr = w >> 1, wc = w & 1;      // wave's 64x64 quadrant
    const int row0 = blockIdx.x * 128;

    f32x4 acc[4][4];
    #pragma unroll
    for (int i = 0; i < 4; ++i)
        #pragma unroll
        for (int jn = 0; jn < 4; ++jn) acc[i][jn] = f32x4{0.f, 0.f, 0.f, 0.f};

    // staging geometry: wave w stages A tiles mt=2w,2w+1 (hi and lo)
    const int arow0 = row0 + (2 * w) * 16 + (lane & 15);
    const int arow1 = row0 + (2 * w + 1) * 16 + (lane & 15);
    const int asub  = (lane >> 4) * 8;

#define STAGE_A(CH, BUF)                                                          \
    {                                                                             \
        const int kc_ = (CH) * 32;                                                \
        const ushort* sH_; const ushort* sL_; size_t stride_; int kloc_;          \
        if (kc_ < 128) { sH_ = h_hi; sL_ = h_lo; stride_ = DD;  kloc_ = kc_; }    \
        else { sH_ = aggF_hi; sL_ = aggF_lo; stride_ = 384; kloc_ = kc_ - 128; }  \
        GLOAD_LDS16(sH_ + (size_t)arow0 * stride_ + kloc_ + asub, &Ah[BUF][(2 * w) * 512]);     \
        GLOAD_LDS16(sH_ + (size_t)arow1 * stride_ + kloc_ + asub, &Ah[BUF][(2 * w + 1) * 512]); \
        GLOAD_LDS16(sL_ + (size_t)arow0 * stride_ + kloc_ + asub, &Al[BUF][(2 * w) * 512]);     \
        GLOAD_LDS16(sL_ + (size_t)arow1 * stride_ + kloc_ + asub, &Al[BUF][(2 * w + 1) * 512]); \
    }

    STAGE_A(0, 0);
    __syncthreads();                        // drain prologue stage

    for (int ch = 0; ch < 16; ++ch) {
        const int cur = ch & 1;
        if (ch < 15) STAGE_A(ch + 1, cur ^ 1);   // prefetch next chunk (in flight)

        // ---- B frags direct global->VGPR (fragment-linear, L2-hot) ----
        short8 bh[4], blo[4];
        #pragma unroll
        for (int jn = 0; jn < 4; ++jn) {
            const size_t base = ((size_t)(ch * 8 + wc * 4 + jn) * 64 + lane) * 8;
            bh[jn]  = *reinterpret_cast<const short8*>(bimg_hi + base);
            blo[jn] = *reinterpret_cast<const short8*>(bimg_lo + base);
        }
        // ---- A frags from LDS ----
        short8 ah[4], al[4];
        #pragma unroll
        for (int i = 0; i < 4; ++i) {
            const int mt = wr * 4 + i;
            ah[i] = *reinterpret_cast<const short8*>(&Ah[cur][mt * 512 + lane * 8]);
            al[i] = *reinterpret_cast<const short8*>(&Al[cur][mt * 512 + lane * 8]);
        }
        // ---- 4x4 frags x 3 MFMAs ----
        #pragma unroll
        for (int i = 0; i < 4; ++i)
            #pragma unroll
            for (int jn = 0; jn < 4; ++jn) {
                acc[i][jn] = __builtin_amdgcn_mfma_f32_16x16x32_bf16(ah[i], bh[jn],  acc[i][jn], 0, 0, 0);
                acc[i][jn] = __builtin_amdgcn_mfma_f32_16x16x32_bf16(ah[i], blo[jn], acc[i][jn], 0, 0, 0);
                acc[i][jn] = __builtin_amdgcn_mfma_f32_16x16x32_bf16(al[i], bh[jn],  acc[i][jn], 0, 0, 0);
            }
        __syncthreads();                    // read-done + drain prefetch
    }
#undef STAGE_A

    // ---- epilogue: C/D layout col=lane&15, row=(lane>>4)*4+reg ----
    const int colb = wc * 64 + (lane & 15);
    const int rowb = row0 + wr * 64 + (lane >> 4) * 4;
    #pragma unroll
    for (int i = 0; i < 4; ++i) {
        #pragma unroll
        for (int jn = 0; jn < 4; ++jn) {
            const int col = colb + jn * 16;
            const float bb = bl[col];
            #pragma unroll
            for (int rr = 0; rr < 4; ++rr) {
                const int row = rowb + i * 16 + rr;
                if (row < nNodes) {
                    const float v = acc[i][jn][rr] + bb;
                    if (isFinal) {
                        out_f32[(size_t)row * DD + col] = v;
                    } else {
                        ushort hi, lo; splitbf(v, hi, lo);
                        out_hi[(size_t)row * DD + col] = hi;
                        out_lo[(size_t)row * DD + col] = lo;
                    }
                }
            }
        }
    }
}

// ============================ Launch =======================================
extern "C" void kernel_launch(void* const* d_in, const int* in_sizes, int n_in,
                              void* d_out, int out_size, void* d_ws, size_t ws_size,
                              hipStream_t stream) {
    const float* feat  = (const float*)d_in[0];   // [N,128]
    const float* W     = (const float*)d_in[1];   // [3,3,128,128]
    const float* Wself = (const float*)d_in[2];   // [3,128,128]
    const float* bias  = (const float*)d_in[3];   // [3,128]
    const int*   src   = (const int*)d_in[4];
    const int*   dst   = (const int*)d_in[5];
    const int*   et    = (const int*)d_in[6];
    float* out = (float*)d_out;

    const int nNodes = in_sizes[0] / DD;
    const int nEdges = in_sizes[4];
    const int nBins  = nNodes * 3;

    // ---- workspace layout (ushort-first, ints after) ----
    ushort* h_hi    = (ushort*)d_ws;                       // N*128
    ushort* h_lo    = h_hi + (size_t)nNodes * DD;          // N*128
    ushort* aggF_hi = h_lo + (size_t)nNodes * DD;          // N*384
    ushort* aggF_lo = aggF_hi + (size_t)nNodes * 384;      // N*384
    ushort* bimg_hi = aggF_lo + (size_t)nNodes * 384;      // 3*65536
    ushort* bimg_lo = bimg_hi + 3 * 65536;                 // 3*65536
    int* ip = (int*)(bimg_lo + 3 * 65536);
    int* deg3     = ip;                                    // 3N
    int* off3     = deg3 + nBins;                          // 3N+1
    int* pos3     = off3 + nBins + 1;                      // 3N
    int* chunkSum = pos3 + nBins;                          // 512
    int* csr      = chunkSum + 512;                        // E

    const int nChunks = (nBins + 1023) / 1024;
    const int nEB = (nEdges + 255) / 256;
    const int nBB = (nBins + 255) / 256;

    // ---- prep ----
    const int n4 = nNodes * DD / 4;
    k_split_feat<<<(n4 + 255) / 256, 256, 0, stream>>>(feat, h_hi, h_lo, n4);
    k_build_bimg<<<(3 * 65536 + 255) / 256, 256, 0, stream>>>(W, Wself, bimg_hi, bimg_lo);

    // ---- CSR build over (dst,rel) bins ----
    k_zero    <<<nBB, 256, 0, stream>>>(deg3, nBins);
    k_hist3   <<<nEB, 256, 0, stream>>>(dst, et, deg3, nEdges);
    k_scanA   <<<nChunks, 1024, 0, stream>>>(deg3, off3, chunkSum, nBins);
    k_scanB   <<<1, 512, 0, stream>>>(chunkSum, nChunks);
    k_scanC   <<<nBB, 256, 0, stream>>>(off3, pos3, chunkSum, nBins, nEdges);
    k_scatter3<<<nEB, 256, 0, stream>>>(src, dst, et, pos3, csr, nEdges);

    // ---- 3 layers: gather then GEMM (in-place h update; final -> d_out) ----
    const int gatherBlocks = (nNodes + 7) / 8;     // 8 nodes / 256-thread block
    const int gemmBlocks   = (nNodes + 127) / 128;

    for (int l = 0; l < 3; ++l) {
        rgcn_gather<<<gatherBlocks, 256, 0, stream>>>(
            h_hi, h_lo, off3, csr, aggF_hi, aggF_lo, nNodes);
        rgcn_mfma<<<gemmBlocks, 256, 0, stream>>>(
            h_hi, h_lo, aggF_hi, aggF_lo,
            bimg_hi + l * 65536, bimg_lo + l * 65536,
            bias + (size_t)l * DD,
            h_hi, h_lo, out, (l == 2) ? 1 : 0, nNodes);
    }
}

// Round 10
// 903.996 us; speedup vs baseline: 1.0157x; 1.0157x over previous
//
#include <hip/hip_runtime.h>

// RGCN 3-layer forward, MI355X — aggregate-first + bf16x3 split-precision MFMA.
// h/aggF stored INTERLEAVED: one uint per element = (hi_bf16) | (lo_bf16 << 16).
//   - gather: one 16B load per lane per row; non-temporal aggF writes (protect
//     the L3-resident h working set from write-stream eviction).
//   - GEMM: A staged via global_load_lds (per-lane src pre-arranged to fragment
//     order), deinterleaved in-register; B from fragment-linear global image.
//   - epilogue: one packed dword store per element (coalesced 64B segments).
// 3 MFMAs per product: hi*hi + hi*lo + lo*hi (lo*lo ~2^-16 dropped), fp32 acc.

#define DD 128

typedef __attribute__((ext_vector_type(8))) short short8;   // 8 bf16 = 4 VGPRs
typedef __attribute__((ext_vector_type(4))) float f32x4;
typedef __attribute__((ext_vector_type(4))) unsigned int u32x4;

__device__ __forceinline__ float bf2f(ushort u) {
    return __uint_as_float(((unsigned)u) << 16);
}
__device__ __forceinline__ ushort f2bf(float f) {            // round-to-nearest-even
    unsigned b = __float_as_uint(f);
    return (ushort)((b + 0x7FFFu + ((b >> 16) & 1u)) >> 16);
}
// pack: low16 = hi bf16, high16 = lo bf16
__device__ __forceinline__ unsigned packbf(float f) {
    ushort hi = f2bf(f);
    ushort lo = f2bf(f - bf2f(hi));
    return (unsigned)hi | ((unsigned)lo << 16);
}
__device__ __forceinline__ float hi_f(unsigned u) { return __uint_as_float(u << 16); }
__device__ __forceinline__ float lo_f(unsigned u) { return __uint_as_float(u & 0xffff0000u); }
__device__ __forceinline__ float both_f(unsigned u) { return hi_f(u) + lo_f(u); }

#define GLOAD_LDS16(g, l)                                                      \
    __builtin_amdgcn_global_load_lds(                                          \
        (const __attribute__((address_space(1))) void*)(g),                    \
        (__attribute__((address_space(3))) void*)(l), 16, 0, 0)

// ===================== prep: features -> interleaved hi/lo ==================
__global__ __launch_bounds__(256) void k_split_feat(
    const float* __restrict__ feat, unsigned* __restrict__ h_il, int n4)
{
    int i = blockIdx.x * 256 + threadIdx.x;
    if (i >= n4) return;
    float4 v = reinterpret_cast<const float4*>(feat)[i];
    u32x4 p;
    p.x = packbf(v.x); p.y = packbf(v.y); p.z = packbf(v.z); p.w = packbf(v.w);
    reinterpret_cast<u32x4*>(h_il)[i] = p;
}

// ===================== prep: weights -> MFMA-fragment-linear image ==========
// bimg[l][chunk c][group g][lane v][j] = B[k = c*32 + (v>>4)*8 + j][col = g*16 + (v&15)]
// B rows 0-127 = Wself[l], rows 128-511 = W[l] (r-major, i-major). Separate hi/lo.
__global__ __launch_bounds__(256) void k_build_bimg(
    const float* __restrict__ W, const float* __restrict__ Wself,
    ushort* __restrict__ bh, ushort* __restrict__ bl_)
{
    int idx = blockIdx.x * 256 + threadIdx.x;
    if (idx >= 3 * 65536) return;
    int l = idx >> 16, rem = idx & 65535;
    int j = rem & 7, v = (rem >> 3) & 63, g = (rem >> 9) & 7, c = (rem >> 12) & 15;
    int col = g * 16 + (v & 15);
    int k = c * 32 + ((v >> 4) * 8) + j;
    float val;
    if (k < 128) val = Wself[((size_t)l * 128 + k) * 128 + col];
    else {
        int kk = k - 128, r = kk >> 7, i = kk & 127;
        val = W[(((size_t)l * 3 + r) * 128 + i) * 128 + col];
    }
    ushort hi = f2bf(val);
    ushort lo = f2bf(val - bf2f(hi));
    bh[idx] = hi; bl_[idx] = lo;
}

// ===================== CSR build over 3N bins (bin = dst*3 + et) ============
__global__ __launch_bounds__(256) void k_zero(int* __restrict__ p, int n) {
    int i = blockIdx.x * 256 + threadIdx.x;
    if (i < n) p[i] = 0;
}
__global__ __launch_bounds__(256) void k_hist3(
    const int* __restrict__ dst, const int* __restrict__ et,
    int* __restrict__ deg, int nEdges) {
    int e = blockIdx.x * 256 + threadIdx.x;
    if (e < nEdges) atomicAdd(&deg[dst[e] * 3 + et[e]], 1);
}
__global__ __launch_bounds__(1024) void k_scanA(
    const int* __restrict__ deg, int* __restrict__ off,
    int* __restrict__ chunkSum, int n) {
    __shared__ int s[1024];
    const int tid = threadIdx.x;
    const int i = blockIdx.x * 1024 + tid;
    int v = (i < n) ? deg[i] : 0;
    s[tid] = v;
    __syncthreads();
    for (int o = 1; o < 1024; o <<= 1) {
        int t = (tid >= o) ? s[tid - o] : 0;
        __syncthreads();
        s[tid] += t;
        __syncthreads();
    }
    if (i < n) off[i] = s[tid] - v;
    if (tid == 1023) chunkSum[blockIdx.x] = s[1023];
}
__global__ __launch_bounds__(512) void k_scanB(int* __restrict__ chunkSum, int nChunks) {
    __shared__ int s[512];
    const int tid = threadIdx.x;
    int v = (tid < nChunks) ? chunkSum[tid] : 0;
    s[tid] = v;
    __syncthreads();
    for (int o = 1; o < 512; o <<= 1) {
        int t = (tid >= o) ? s[tid - o] : 0;
        __syncthreads();
        s[tid] += t;
        __syncthreads();
    }
    if (tid < nChunks) chunkSum[tid] = s[tid] - v;
}
__global__ __launch_bounds__(256) void k_scanC(
    int* __restrict__ off, int* __restrict__ pos,
    const int* __restrict__ chunkBase, int n, int total) {
    int i = blockIdx.x * 256 + threadIdx.x;
    if (i < n) {
        int o = off[i] + chunkBase[i >> 10];
        off[i] = o;
        pos[i] = o;
    }
    if (i == 0) off[n] = total;
}
__global__ __launch_bounds__(256) void k_scatter3(
    const int* __restrict__ src, const int* __restrict__ dst,
    const int* __restrict__ et, int* __restrict__ pos,
    int* __restrict__ csr, int nEdges) {
    int e = blockIdx.x * 256 + threadIdx.x;
    if (e < nEdges) {
        int j = atomicAdd(&pos[dst[e] * 3 + et[e]], 1);
        csr[j] = src[e];
    }
}

// ===================== gather: aggF[n,r,:] = sum h[src] =====================
// One 32-lane half-wave per dst node; lane owns elements li*4..li*4+3.
// Interleaved h: ONE 16B load per row per lane. Non-temporal aggF stores.
__global__ __launch_bounds__(256) void rgcn_gather(
    const unsigned* __restrict__ h_il,
    const int* __restrict__ off3, const int* __restrict__ csr,
    unsigned* __restrict__ aggF_il,
    int nNodes)
{
    const int gtid = blockIdx.x * 256 + threadIdx.x;
    const int gw   = gtid >> 6;
    const int lane = threadIdx.x & 63;
    const int sub  = lane >> 5;
    const int li   = lane & 31;
    const int n    = gw * 2 + sub;
    if (n >= nNodes) return;
    const int e0 = li * 4;

    #pragma unroll
    for (int r = 0; r < 3; ++r) {
        const int b = off3[n * 3 + r];
        const int e = off3[n * 3 + r + 1];
        float ax = 0.f, ay = 0.f, az = 0.f, aw = 0.f;
        int j = b;
        for (; j + 3 < e; j += 4) {
            int s0 = csr[j], s1 = csr[j + 1], s2 = csr[j + 2], s3 = csr[j + 3];
            u32x4 v0 = *reinterpret_cast<const u32x4*>(h_il + (size_t)s0 * DD + e0);
            u32x4 v1 = *reinterpret_cast<const u32x4*>(h_il + (size_t)s1 * DD + e0);
            u32x4 v2 = *reinterpret_cast<const u32x4*>(h_il + (size_t)s2 * DD + e0);
            u32x4 v3 = *reinterpret_cast<const u32x4*>(h_il + (size_t)s3 * DD + e0);
            ax += (both_f(v0.x) + both_f(v1.x)) + (both_f(v2.x) + both_f(v3.x));
            ay += (both_f(v0.y) + both_f(v1.y)) + (both_f(v2.y) + both_f(v3.y));
            az += (both_f(v0.z) + both_f(v1.z)) + (both_f(v2.z) + both_f(v3.z));
            aw += (both_f(v0.w) + both_f(v1.w)) + (both_f(v2.w) + both_f(v3.w));
        }
        for (; j < e; ++j) {
            int s0 = csr[j];
            u32x4 v0 = *reinterpret_cast<const u32x4*>(h_il + (size_t)s0 * DD + e0);
            ax += both_f(v0.x); ay += both_f(v0.y);
            az += both_f(v0.z); aw += both_f(v0.w);
        }
        u32x4 p;
        p.x = packbf(ax); p.y = packbf(ay); p.z = packbf(az); p.w = packbf(aw);
        __builtin_nontemporal_store(
            p, reinterpret_cast<u32x4*>(aggF_il + (size_t)n * 384 + r * DD + e0));
    }
}

// ===================== MFMA GEMM: [h|aggF] @ Bfused + bias ==================
// 128x128 tile per block, 4 waves (2x2), each wave 64x64 = 4x4 frags of 16x16.
// A interleaved; staged fragment-ordered via per-lane global src so that LDS
// reads are lane-linear (l*16B). In-register deinterleave -> ah/al short8.
__global__ __launch_bounds__(256) void rgcn_mfma(
    const unsigned* __restrict__ h_il,                                      // [N,128]
    const unsigned* __restrict__ aggF_il,                                   // [N,384]
    const ushort* __restrict__ bimg_hi, const ushort* __restrict__ bimg_lo, // layer's 65536
    const float* __restrict__ bl,                                           // [128]
    unsigned* __restrict__ out_il,                                          // layers 0,1
    float* __restrict__ out_f32,                                            // layer 2
    int isFinal, int nNodes)
{
    __shared__ unsigned As[2][4096];        // 2 bufs x 8 tiles x 512 uints = 32 KB

    const int t = threadIdx.x;
    const int w = t >> 6;                   // wave 0..3
    const int lane = t & 63;
    const int wr = w >> 1, wc = w & 1;      // wave's 64x64 quadrant
    const int row0 = blockIdx.x * 128;

    f32x4 acc[4][4];
    #pragma unroll
    for (int i = 0; i < 4; ++i)
        #pragma unroll
        for (int jn = 0; jn < 4; ++jn) acc[i][jn] = f32x4{0.f, 0.f, 0.f, 0.f};

    // staging: wave w stages tiles mt=2w,2w+1. Per tile two gloads:
    //   gload0: lane -> (row = l&15, k = k0(l)..k0(l)+3), k0 = (l>>4)*8  -> region0
    //   gload1: lane -> k0+4..k0+7                                       -> region1
    // so ds_read at lane*16B yields exactly the lane's fragment halves.
    const int arow0 = row0 + (2 * w) * 16 + (lane & 15);
    const int arow1 = row0 + (2 * w + 1) * 16 + (lane & 15);
    const int ak    = (lane >> 4) * 8;

#define STAGE_A(CH, BUF)                                                           \
    {                                                                              \
        const int kc_ = (CH) * 32;                                                 \
        const unsigned* sP_; int strideU_; int kloc_;                              \
        if (kc_ < 128) { sP_ = h_il; strideU_ = DD; kloc_ = kc_; }                 \
        else { sP_ = aggF_il; strideU_ = 384; kloc_ = kc_ - 128; }                 \
        const unsigned* s0_ = sP_ + (size_t)arow0 * strideU_ + kloc_ + ak;         \
        const unsigned* s1_ = sP_ + (size_t)arow1 * strideU_ + kloc_ + ak;         \
        GLOAD_LDS16(s0_,     &As[BUF][(2 * w) * 512]);                             \
        GLOAD_LDS16(s0_ + 4, &As[BUF][(2 * w) * 512 + 256]);                       \
        GLOAD_LDS16(s1_,     &As[BUF][(2 * w + 1) * 512]);                         \
        GLOAD_LDS16(s1_ + 4, &As[BUF][(2 * w + 1) * 512 + 256]);                   \
    }

    STAGE_A(0, 0);
    __syncthreads();                        // drain prologue stage

    for (int ch = 0; ch < 16; ++ch) {
        const int cur = ch & 1;
        if (ch < 15) STAGE_A(ch + 1, cur ^ 1);   // prefetch next chunk

        // ---- B frags direct global->VGPR (fragment-linear, L2-hot) ----
        short8 bh[4], blo[4];
        #pragma unroll
        for (int jn = 0; jn < 4; ++jn) {
            const size_t base = ((size_t)(ch * 8 + wc * 4 + jn) * 64 + lane) * 8;
            bh[jn]  = *reinterpret_cast<const short8*>(bimg_hi + base);
            blo[jn] = *reinterpret_cast<const short8*>(bimg_lo + base);
        }
        // ---- A frags from LDS: 2x b128 + in-register deinterleave ----
        short8 ah[4], al[4];
        #pragma unroll
        for (int i = 0; i < 4; ++i) {
            const unsigned* tb = &As[cur][(wr * 4 + i) * 512];
            u32x4 q0 = *reinterpret_cast<const u32x4*>(tb + lane * 4);
            u32x4 q1 = *reinterpret_cast<const u32x4*>(tb + 256 + lane * 4);
            u32x4 AH, AL;
            AH.x = (q0.x & 0xffffu) | (q0.y << 16);
            AH.y = (q0.z & 0xffffu) | (q0.w << 16);
            AH.z = (q1.x & 0xffffu) | (q1.y << 16);
            AH.w = (q1.z & 0xffffu) | (q1.w << 16);
            AL.x = (q0.x >> 16) | (q0.y & 0xffff0000u);
            AL.y = (q0.z >> 16) | (q0.w & 0xffff0000u);
            AL.z = (q1.x >> 16) | (q1.y & 0xffff0000u);
            AL.w = (q1.z >> 16) | (q1.w & 0xffff0000u);
            ah[i] = __builtin_bit_cast(short8, AH);
            al[i] = __builtin_bit_cast(short8, AL);
        }
        // ---- 4x4 frags x 3 MFMAs ----
        #pragma unroll
        for (int i = 0; i < 4; ++i)
            #pragma unroll
            for (int jn = 0; jn < 4; ++jn) {
                acc[i][jn] = __builtin_amdgcn_mfma_f32_16x16x32_bf16(ah[i], bh[jn],  acc[i][jn], 0, 0, 0);
                acc[i][jn] = __builtin_amdgcn_mfma_f32_16x16x32_bf16(ah[i], blo[jn], acc[i][jn], 0, 0, 0);
                acc[i][jn] = __builtin_amdgcn_mfma_f32_16x16x32_bf16(al[i], bh[jn],  acc[i][jn], 0, 0, 0);
            }
        __syncthreads();                    // readers done + prefetch drained
    }
#undef STAGE_A

    // ---- epilogue: C/D layout col=lane&15, row=(lane>>4)*4+reg ----
    const int colb = wc * 64 + (lane & 15);
    const int rowb = row0 + wr * 64 + (lane >> 4) * 4;
    #pragma unroll
    for (int i = 0; i < 4; ++i) {
        #pragma unroll
        for (int jn = 0; jn < 4; ++jn) {
            const int col = colb + jn * 16;
            const float bb = bl[col];
            #pragma unroll
            for (int rr = 0; rr < 4; ++rr) {
                const int row = rowb + i * 16 + rr;
                if (row < nNodes) {
                    const float v = acc[i][jn][rr] + bb;
                    if (isFinal) {
                        __builtin_nontemporal_store(v, out_f32 + (size_t)row * DD + col);
                    } else {
                        out_il[(size_t)row * DD + col] = packbf(v);
                    }
                }
            }
        }
    }
}

// ============================ Launch =======================================
extern "C" void kernel_launch(void* const* d_in, const int* in_sizes, int n_in,
                              void* d_out, int out_size, void* d_ws, size_t ws_size,
                              hipStream_t stream) {
    const float* feat  = (const float*)d_in[0];   // [N,128]
    const float* W     = (const float*)d_in[1];   // [3,3,128,128]
    const float* Wself = (const float*)d_in[2];   // [3,128,128]
    const float* bias  = (const float*)d_in[3];   // [3,128]
    const int*   src   = (const int*)d_in[4];
    const int*   dst   = (const int*)d_in[5];
    const int*   et    = (const int*)d_in[6];
    float* out = (float*)d_out;

    const int nNodes = in_sizes[0] / DD;
    const int nEdges = in_sizes[4];
    const int nBins  = nNodes * 3;

    // ---- workspace layout ----
    unsigned* h_il    = (unsigned*)d_ws;                   // N*128 uints
    unsigned* aggF_il = h_il + (size_t)nNodes * DD;        // N*384 uints
    ushort* bimg_hi   = (ushort*)(aggF_il + (size_t)nNodes * 384);  // 3*65536
    ushort* bimg_lo   = bimg_hi + 3 * 65536;               // 3*65536
    int* ip = (int*)(bimg_lo + 3 * 65536);
    int* deg3     = ip;                                    // 3N
    int* off3     = deg3 + nBins;                          // 3N+1
    int* pos3     = off3 + nBins + 1;                      // 3N
    int* chunkSum = pos3 + nBins;                          // 512
    int* csr      = chunkSum + 512;                        // E

    const int nChunks = (nBins + 1023) / 1024;
    const int nEB = (nEdges + 255) / 256;
    const int nBB = (nBins + 255) / 256;

    // ---- prep ----
    const int n4 = nNodes * DD / 4;
    k_split_feat<<<(n4 + 255) / 256, 256, 0, stream>>>(feat, h_il, n4);
    k_build_bimg<<<(3 * 65536 + 255) / 256, 256, 0, stream>>>(W, Wself, bimg_hi, bimg_lo);

    // ---- CSR build over (dst,rel) bins ----
    k_zero    <<<nBB, 256, 0, stream>>>(deg3, nBins);
    k_hist3   <<<nEB, 256, 0, stream>>>(dst, et, deg3, nEdges);
    k_scanA   <<<nChunks, 1024, 0, stream>>>(deg3, off3, chunkSum, nBins);
    k_scanB   <<<1, 512, 0, stream>>>(chunkSum, nChunks);
    k_scanC   <<<nBB, 256, 0, stream>>>(off3, pos3, chunkSum, nBins, nEdges);
    k_scatter3<<<nEB, 256, 0, stream>>>(src, dst, et, pos3, csr, nEdges);

    // ---- 3 layers: gather then GEMM (in-place h update; final -> d_out) ----
    const int gatherBlocks = (nNodes + 7) / 8;     // 8 nodes / 256-thread block
    const int gemmBlocks   = (nNodes + 127) / 128;

    for (int l = 0; l < 3; ++l) {
        rgcn_gather<<<gatherBlocks, 256, 0, stream>>>(
            h_il, off3, csr, aggF_il, nNodes);
        rgcn_mfma<<<gemmBlocks, 256, 0, stream>>>(
            h_il, aggF_il,
            bimg_hi + l * 65536, bimg_lo + l * 65536,
            bias + (size_t)l * DD,
            h_il, out, (l == 2) ? 1 : 0, nNodes);
    }
}